// Round 1
// baseline (3219.306 us; speedup 1.0000x reference)
//
#include <hip/hip_runtime.h>

#define N_NODES 50000
#define N_EDGES 600000
#define HID 128

// ---------------- degree / dinv ----------------

__global__ __launch_bounds__(256) void k_count_deg(const int* __restrict__ dst,
                                                   int* __restrict__ deg) {
    int e = blockIdx.x * 256 + threadIdx.x;
    if (e < N_EDGES) atomicAdd(&deg[dst[e]], 1);
}

__global__ __launch_bounds__(256) void k_make_dinv(const int* __restrict__ deg,
                                                   float* __restrict__ dinv) {
    int i = blockIdx.x * 256 + threadIdx.x;
    if (i < N_NODES) dinv[i] = rsqrtf((float)(deg[i] + 1));  // +1 self-loop
}

// ---------------- GEMM: hs = (X @ W) * dinv[row] ----------------
// X: [N,128] fp32, W: [128,128] fp32 row-major [k][col], hs: [N,128]
// block = 256 threads, tile = 64 rows x 128 cols, thread = 4 rows x 8 cols

__global__ __launch_bounds__(256) void k_gemm_scale(const float* __restrict__ X,
                                                    const float* __restrict__ W,
                                                    const float* __restrict__ dinv,
                                                    float* __restrict__ HS) {
    __shared__ float Wl[HID][HID];   // 64 KB, [k][col]
    __shared__ float Xl[64][132];    // padded stride 132 (16B aligned rows, bank-spread)

    const int tid = threadIdx.x;
    const int row0 = blockIdx.x * 64;

    // cooperative load W (4096 float4)
    const float4* Wg = (const float4*)W;
    float4* Wl4 = (float4*)&Wl[0][0];
#pragma unroll
    for (int j = 0; j < 16; ++j) Wl4[tid + j * 256] = Wg[tid + j * 256];

    // cooperative load X tile (2048 float4), zero-pad OOB rows
#pragma unroll
    for (int j = 0; j < 8; ++j) {
        int idx = tid + j * 256;
        int r = idx >> 5, p = idx & 31;
        float4 v = make_float4(0.f, 0.f, 0.f, 0.f);
        if (row0 + r < N_NODES) v = ((const float4*)X)[(size_t)(row0 + r) * 32 + p];
        *(float4*)&Xl[r][p * 4] = v;
    }
    __syncthreads();

    const int tx = tid & 15;    // col group: cols tx*8 .. tx*8+7
    const int ty = tid >> 4;    // row group: rows ty*4 .. ty*4+3
    const int c0 = tx * 8;
    const int r0 = ty * 4;

    float acc[4][8];
#pragma unroll
    for (int i = 0; i < 4; ++i)
#pragma unroll
        for (int j = 0; j < 8; ++j) acc[i][j] = 0.f;

    for (int k = 0; k < HID; k += 4) {
        float4 xa[4];
#pragma unroll
        for (int i = 0; i < 4; ++i) xa[i] = *(const float4*)&Xl[r0 + i][k];
#pragma unroll
        for (int kk = 0; kk < 4; ++kk) {
            float4 w0 = *(const float4*)&Wl[k + kk][c0];
            float4 w1 = *(const float4*)&Wl[k + kk][c0 + 4];
            float wv[8] = {w0.x, w0.y, w0.z, w0.w, w1.x, w1.y, w1.z, w1.w};
            float xv[4] = {(&xa[0].x)[kk], (&xa[1].x)[kk], (&xa[2].x)[kk], (&xa[3].x)[kk]};
#pragma unroll
            for (int i = 0; i < 4; ++i)
#pragma unroll
                for (int j = 0; j < 8; ++j) acc[i][j] = fmaf(xv[i], wv[j], acc[i][j]);
        }
    }

    // epilogue: scale by dinv[row], store
#pragma unroll
    for (int i = 0; i < 4; ++i) {
        int r = row0 + r0 + i;
        if (r < N_NODES) {
            float dv = dinv[r];
            float4 o0 = make_float4(acc[i][0] * dv, acc[i][1] * dv, acc[i][2] * dv, acc[i][3] * dv);
            float4 o1 = make_float4(acc[i][4] * dv, acc[i][5] * dv, acc[i][6] * dv, acc[i][7] * dv);
            float4* out = (float4*)&HS[(size_t)r * HID + c0];
            out[0] = o0;
            out[1] = o1;
        }
    }
}

// ---------------- edge scatter: acc[dst] += hs[src] ----------------
// one thread per (edge, 4-float chunk): 32 threads per edge

__global__ __launch_bounds__(256) void k_scatter(const int* __restrict__ src,
                                                 const int* __restrict__ dst,
                                                 const float* __restrict__ hs,
                                                 float* __restrict__ acc) {
    int idx = blockIdx.x * 256 + threadIdx.x;
    int e = idx >> 5;
    if (e >= N_EDGES) return;
    int c = (idx & 31) << 2;
    int s = src[e], d = dst[e];
    float4 v = *(const float4*)&hs[(size_t)s * HID + c];
    float* a = &acc[(size_t)d * HID + c];
    atomicAdd(a + 0, v.x);
    atomicAdd(a + 1, v.y);
    atomicAdd(a + 2, v.z);
    atomicAdd(a + 3, v.w);
}

// ---------------- finalize: out = [relu](b + dinv[i]*(acc + hs)) ----------------

template <bool RELU>
__global__ __launch_bounds__(256) void k_finalize(const float* __restrict__ accIn,
                                                  const float* __restrict__ hs,
                                                  const float* __restrict__ dinv,
                                                  const float* __restrict__ bias,
                                                  float* __restrict__ out) {
    int idx = blockIdx.x * 256 + threadIdx.x;  // float4 index
    if (idx >= N_NODES * 32) return;
    int i = idx >> 5;
    int c = (idx & 31) * 4;
    float dv = dinv[i];
    float4 a = ((const float4*)accIn)[idx];
    float4 h = ((const float4*)hs)[idx];
    float4 bb = *(const float4*)&bias[c];
    float4 o;
    o.x = bb.x + dv * (a.x + h.x);
    o.y = bb.y + dv * (a.y + h.y);
    o.z = bb.z + dv * (a.z + h.z);
    o.w = bb.w + dv * (a.w + h.w);
    if (RELU) {
        o.x = fmaxf(o.x, 0.f);
        o.y = fmaxf(o.y, 0.f);
        o.z = fmaxf(o.z, 0.f);
        o.w = fmaxf(o.w, 0.f);
    }
    ((float4*)out)[idx] = o;
}

// ---------------- launch ----------------

extern "C" void kernel_launch(void* const* d_in, const int* in_sizes, int n_in,
                              void* d_out, int out_size, void* d_ws, size_t ws_size,
                              hipStream_t stream) {
    const int* edge_index = (const int*)d_in[0];       // [2, E]
    const float* node_emb = (const float*)d_in[1];     // [N, 128]
    const float* W0 = (const float*)d_in[2];
    const float* b0 = (const float*)d_in[3];
    const float* W1 = (const float*)d_in[4];
    const float* b1 = (const float*)d_in[5];
    const float* W2 = (const float*)d_in[6];
    const float* b2 = (const float*)d_in[7];
    float* out = (float*)d_out;

    const int* src = edge_index;            // edge_index[0]
    const int* dst = edge_index + N_EDGES;  // edge_index[1]

    // workspace layout (floats)
    float* ws = (float*)d_ws;
    float* dinv = ws;                                   // N
    int* deg = (int*)(ws + N_NODES);                    // N
    float* hs = ws + 2 * N_NODES;                       // N*H   (offset 400000 B, 16B aligned)
    float* acc = hs + (size_t)N_NODES * HID;            // N*H

    const int gemm_blocks = (N_NODES + 63) / 64;            // 782
    const int scat_blocks = (N_EDGES * 32 + 255) / 256;     // 75000
    const int fin_blocks = (N_NODES * 32 + 255) / 256;      // 6250
    const int cnt_blocks = (N_EDGES + 255) / 256;           // 2344
    const int nod_blocks = (N_NODES + 255) / 256;           // 196

    // degree + dinv
    hipMemsetAsync(deg, 0, N_NODES * sizeof(int), stream);
    k_count_deg<<<cnt_blocks, 256, 0, stream>>>(dst, deg);
    k_make_dinv<<<nod_blocks, 256, 0, stream>>>(deg, dinv);

    const size_t nh_bytes = (size_t)N_NODES * HID * sizeof(float);

    // ---- layer 0 ----
    k_gemm_scale<<<gemm_blocks, 256, 0, stream>>>(node_emb, W0, dinv, hs);
    hipMemsetAsync(acc, 0, nh_bytes, stream);
    k_scatter<<<scat_blocks, 256, 0, stream>>>(src, dst, hs, acc);
    k_finalize<true><<<fin_blocks, 256, 0, stream>>>(acc, hs, dinv, b0, acc);

    // ---- layer 1 ----
    k_gemm_scale<<<gemm_blocks, 256, 0, stream>>>(acc, W1, dinv, hs);
    hipMemsetAsync(acc, 0, nh_bytes, stream);
    k_scatter<<<scat_blocks, 256, 0, stream>>>(src, dst, hs, acc);
    k_finalize<true><<<fin_blocks, 256, 0, stream>>>(acc, hs, dinv, b1, acc);

    // ---- layer 2 ----
    k_gemm_scale<<<gemm_blocks, 256, 0, stream>>>(acc, W2, dinv, hs);
    hipMemsetAsync(acc, 0, nh_bytes, stream);
    k_scatter<<<scat_blocks, 256, 0, stream>>>(src, dst, hs, acc);
    k_finalize<false><<<fin_blocks, 256, 0, stream>>>(acc, hs, dinv, b2, out);
}

// Round 2
// 471.164 us; speedup vs baseline: 6.8327x; 6.8327x over previous
//
#include <hip/hip_runtime.h>

#define N_NODES 50000
#define N_EDGES 600000
#define HID 128

// ---------------- degree ----------------

__global__ __launch_bounds__(256) void k_count_deg(const int* __restrict__ dst,
                                                   int* __restrict__ deg) {
    int e = blockIdx.x * 256 + threadIdx.x;
    if (e < N_EDGES) atomicAdd(&deg[dst[e]], 1);
}

__global__ __launch_bounds__(256) void k_make_dinv(const int* __restrict__ deg,
                                                   float* __restrict__ dinv) {
    int i = blockIdx.x * 256 + threadIdx.x;
    if (i < N_NODES) dinv[i] = rsqrtf((float)(deg[i] + 1));  // +1 self-loop
}

// ---------------- exclusive scan (single block, chunked Hillis-Steele) ----------------

__global__ __launch_bounds__(1024) void k_scan(const int* __restrict__ deg,
                                               int* __restrict__ offs) {
    __shared__ int buf[1024];
    __shared__ int carry;
    const int t = threadIdx.x;
    if (t == 0) carry = 0;
    __syncthreads();
    for (int base = 0; base < N_NODES; base += 1024) {
        int i = base + t;
        int v = (i < N_NODES) ? deg[i] : 0;
        buf[t] = v;
        __syncthreads();
#pragma unroll
        for (int off = 1; off < 1024; off <<= 1) {
            int x = (t >= off) ? buf[t - off] : 0;
            __syncthreads();
            buf[t] += x;
            __syncthreads();
        }
        int incl = buf[t];
        if (i < N_NODES) offs[i] = carry + (incl - v);
        __syncthreads();
        if (t == 1023) carry += incl;
        __syncthreads();
    }
    if (t == 0) offs[N_NODES] = carry;  // == N_EDGES
}

// ---------------- CSR fill ----------------

__global__ __launch_bounds__(256) void k_fill(const int* __restrict__ src,
                                              const int* __restrict__ dst,
                                              const int* __restrict__ offs,
                                              int* __restrict__ cursor,
                                              int* __restrict__ csr) {
    int e = blockIdx.x * 256 + threadIdx.x;
    if (e >= N_EDGES) return;
    int d = dst[e];
    int pos = offs[d] + atomicAdd(&cursor[d], 1);
    csr[pos] = src[e];
}

// ---------------- GEMM: hs = (X @ W) * dinv[row] ----------------
// block = 256 threads, tile = 64 rows x 128 cols, thread = 4 rows x 8 cols

__global__ __launch_bounds__(256) void k_gemm_scale(const float* __restrict__ X,
                                                    const float* __restrict__ W,
                                                    const float* __restrict__ dinv,
                                                    float* __restrict__ HS) {
    __shared__ float Wl[HID][HID];   // 64 KB, [k][col]
    __shared__ float Xl[64][132];    // padded stride

    const int tid = threadIdx.x;
    const int row0 = blockIdx.x * 64;

    const float4* Wg = (const float4*)W;
    float4* Wl4 = (float4*)&Wl[0][0];
#pragma unroll
    for (int j = 0; j < 16; ++j) Wl4[tid + j * 256] = Wg[tid + j * 256];

#pragma unroll
    for (int j = 0; j < 8; ++j) {
        int idx = tid + j * 256;
        int r = idx >> 5, p = idx & 31;
        float4 v = make_float4(0.f, 0.f, 0.f, 0.f);
        if (row0 + r < N_NODES) v = ((const float4*)X)[(size_t)(row0 + r) * 32 + p];
        *(float4*)&Xl[r][p * 4] = v;
    }
    __syncthreads();

    const int tx = tid & 15;
    const int ty = tid >> 4;
    const int c0 = tx * 8;
    const int r0 = ty * 4;

    float acc[4][8];
#pragma unroll
    for (int i = 0; i < 4; ++i)
#pragma unroll
        for (int j = 0; j < 8; ++j) acc[i][j] = 0.f;

    for (int k = 0; k < HID; k += 4) {
        float4 xa[4];
#pragma unroll
        for (int i = 0; i < 4; ++i) xa[i] = *(const float4*)&Xl[r0 + i][k];
#pragma unroll
        for (int kk = 0; kk < 4; ++kk) {
            float4 w0 = *(const float4*)&Wl[k + kk][c0];
            float4 w1 = *(const float4*)&Wl[k + kk][c0 + 4];
            float wv[8] = {w0.x, w0.y, w0.z, w0.w, w1.x, w1.y, w1.z, w1.w};
            float xv[4] = {(&xa[0].x)[kk], (&xa[1].x)[kk], (&xa[2].x)[kk], (&xa[3].x)[kk]};
#pragma unroll
            for (int i = 0; i < 4; ++i)
#pragma unroll
                for (int j = 0; j < 8; ++j) acc[i][j] = fmaf(xv[i], wv[j], acc[i][j]);
        }
    }

#pragma unroll
    for (int i = 0; i < 4; ++i) {
        int r = row0 + r0 + i;
        if (r < N_NODES) {
            float dv = dinv[r];
            float4 o0 = make_float4(acc[i][0] * dv, acc[i][1] * dv, acc[i][2] * dv, acc[i][3] * dv);
            float4 o1 = make_float4(acc[i][4] * dv, acc[i][5] * dv, acc[i][6] * dv, acc[i][7] * dv);
            float4* outp = (float4*)&HS[(size_t)r * HID + c0];
            outp[0] = o0;
            outp[1] = o1;
        }
    }
}

// ---------------- fused gather: out = [relu](b + dinv[i]*(hs[i] + sum_e hs[csr[e]])) ----------------
// 32 lanes per node, one float4 per lane

template <bool RELU>
__global__ __launch_bounds__(256) void k_gather(const float* __restrict__ hs,
                                                const int* __restrict__ csr,
                                                const int* __restrict__ offs,
                                                const float* __restrict__ dinv,
                                                const float* __restrict__ bias,
                                                float* __restrict__ out) {
    int t = blockIdx.x * 256 + threadIdx.x;
    int node = t >> 5;
    if (node >= N_NODES) return;
    int c = (t & 31) * 4;

    float4 a = *(const float4*)&hs[(size_t)node * HID + c];  // self-loop term
    int e0 = offs[node], e1 = offs[node + 1];

    // 2-deep software pipeline over the edge list
    int e = e0;
    for (; e + 2 <= e1; e += 2) {
        int s0 = csr[e], s1 = csr[e + 1];
        float4 v0 = *(const float4*)&hs[(size_t)s0 * HID + c];
        float4 v1 = *(const float4*)&hs[(size_t)s1 * HID + c];
        a.x += v0.x + v1.x;
        a.y += v0.y + v1.y;
        a.z += v0.z + v1.z;
        a.w += v0.w + v1.w;
    }
    if (e < e1) {
        int s0 = csr[e];
        float4 v0 = *(const float4*)&hs[(size_t)s0 * HID + c];
        a.x += v0.x; a.y += v0.y; a.z += v0.z; a.w += v0.w;
    }

    float dv = dinv[node];
    float4 bb = *(const float4*)&bias[c];
    float4 o;
    o.x = bb.x + dv * a.x;
    o.y = bb.y + dv * a.y;
    o.z = bb.z + dv * a.z;
    o.w = bb.w + dv * a.w;
    if (RELU) {
        o.x = fmaxf(o.x, 0.f);
        o.y = fmaxf(o.y, 0.f);
        o.z = fmaxf(o.z, 0.f);
        o.w = fmaxf(o.w, 0.f);
    }
    *(float4*)&out[(size_t)node * HID + c] = o;
}

// ---------------- launch ----------------

extern "C" void kernel_launch(void* const* d_in, const int* in_sizes, int n_in,
                              void* d_out, int out_size, void* d_ws, size_t ws_size,
                              hipStream_t stream) {
    const int* edge_index = (const int*)d_in[0];       // [2, E]
    const float* node_emb = (const float*)d_in[1];     // [N, 128]
    const float* W0 = (const float*)d_in[2];
    const float* b0 = (const float*)d_in[3];
    const float* W1 = (const float*)d_in[4];
    const float* b1 = (const float*)d_in[5];
    const float* W2 = (const float*)d_in[6];
    const float* b2 = (const float*)d_in[7];
    float* out = (float*)d_out;

    const int* src = edge_index;            // edge_index[0]
    const int* dst = edge_index + N_EDGES;  // edge_index[1]

    // workspace layout (persistent): dinv | offsets | csr | hs
    float* ws = (float*)d_ws;
    float* dinv = ws;                                   // N floats
    int* offs = (int*)(ws + N_NODES);                   // N+1 ints
    int* csr = (int*)(ws + 2 * N_NODES + 4);            // E ints
    float* hs = ws + 2 * N_NODES + 4 + N_EDGES;         // N*H floats (16B aligned)

    // transient build scratch, overlapped into hs region (build completes
    // before the first GEMM writes hs; single stream => ordered)
    int* deg = (int*)hs;                                // N ints
    int* cursor = deg + N_NODES;                        // N ints

    const int gemm_blocks = (N_NODES + 63) / 64;            // 782
    const int gath_blocks = (N_NODES * 32 + 255) / 256;     // 6250
    const int edge_blocks = (N_EDGES + 255) / 256;          // 2344
    const int node_blocks = (N_NODES + 255) / 256;          // 196

    // ---- CSR build (once) ----
    hipMemsetAsync(deg, 0, 2 * N_NODES * sizeof(int), stream);  // deg + cursor
    k_count_deg<<<edge_blocks, 256, 0, stream>>>(dst, deg);
    k_make_dinv<<<node_blocks, 256, 0, stream>>>(deg, dinv);
    k_scan<<<1, 1024, 0, stream>>>(deg, offs);
    k_fill<<<edge_blocks, 256, 0, stream>>>(src, dst, offs, cursor, csr);

    // ---- layer 0 ----  (d_out doubles as the inter-layer activation buffer)
    k_gemm_scale<<<gemm_blocks, 256, 0, stream>>>(node_emb, W0, dinv, hs);
    k_gather<true><<<gath_blocks, 256, 0, stream>>>(hs, csr, offs, dinv, b0, out);

    // ---- layer 1 ----
    k_gemm_scale<<<gemm_blocks, 256, 0, stream>>>(out, W1, dinv, hs);
    k_gather<true><<<gath_blocks, 256, 0, stream>>>(hs, csr, offs, dinv, b1, out);

    // ---- layer 2 ----
    k_gemm_scale<<<gemm_blocks, 256, 0, stream>>>(out, W2, dinv, hs);
    k_gather<false><<<gath_blocks, 256, 0, stream>>>(hs, csr, offs, dinv, b2, out);
}

// Round 3
// 388.413 us; speedup vs baseline: 8.2884x; 1.2131x over previous
//
#include <hip/hip_runtime.h>

#define N_NODES 50000
#define N_EDGES 600000
#define HID 128
#define SCAN_BLOCKS ((N_NODES + 255) / 256)   // 196

// ---------------- degree ----------------

__global__ __launch_bounds__(256) void k_count_deg(const int* __restrict__ dst,
                                                   int* __restrict__ deg) {
    int e = blockIdx.x * 256 + threadIdx.x;
    if (e < N_EDGES) atomicAdd(&deg[dst[e]], 1);
}

__global__ __launch_bounds__(256) void k_make_dinv(const int* __restrict__ deg,
                                                   float* __restrict__ dinv) {
    int i = blockIdx.x * 256 + threadIdx.x;
    if (i < N_NODES) dinv[i] = rsqrtf((float)(deg[i] + 1));  // +1 self-loop
}

// ---------------- two-level exclusive scan ----------------

__global__ __launch_bounds__(256) void k_scan1(const int* __restrict__ deg,
                                               int* __restrict__ offs,
                                               int* __restrict__ bsum) {
    __shared__ int buf[256];
    const int t = threadIdx.x;
    const int i = blockIdx.x * 256 + t;
    int v = (i < N_NODES) ? deg[i] : 0;
    buf[t] = v;
    __syncthreads();
#pragma unroll
    for (int off = 1; off < 256; off <<= 1) {
        int x = (t >= off) ? buf[t - off] : 0;
        __syncthreads();
        buf[t] += x;
        __syncthreads();
    }
    if (i < N_NODES) offs[i] = buf[t] - v;       // block-local exclusive
    if (t == 255) bsum[blockIdx.x] = buf[255];   // block total
}

__global__ __launch_bounds__(256) void k_scan2(int* __restrict__ bsum) {
    __shared__ int buf[256];
    const int t = threadIdx.x;
    int v = (t < SCAN_BLOCKS) ? bsum[t] : 0;
    buf[t] = v;
    __syncthreads();
#pragma unroll
    for (int off = 1; off < 256; off <<= 1) {
        int x = (t >= off) ? buf[t - off] : 0;
        __syncthreads();
        buf[t] += x;
        __syncthreads();
    }
    if (t < SCAN_BLOCKS) bsum[t] = buf[t] - v;   // exclusive over block sums
}

__global__ __launch_bounds__(256) void k_scan3(int* __restrict__ offs,
                                               const int* __restrict__ bsum) {
    int i = blockIdx.x * 256 + threadIdx.x;
    if (i < N_NODES) offs[i] += bsum[blockIdx.x];
    if (i == 0) offs[N_NODES] = N_EDGES;         // total is known statically
}

// ---------------- CSR fill ----------------

__global__ __launch_bounds__(256) void k_fill(const int* __restrict__ src,
                                              const int* __restrict__ dst,
                                              const int* __restrict__ offs,
                                              int* __restrict__ cursor,
                                              int* __restrict__ csr) {
    int e = blockIdx.x * 256 + threadIdx.x;
    if (e >= N_EDGES) return;
    int d = dst[e];
    int pos = offs[d] + atomicAdd(&cursor[d], 1);
    csr[pos] = src[e];
}

// ---------------- GEMM: hs = (X @ W) * dinv[row] ----------------

__global__ __launch_bounds__(256) void k_gemm_scale(const float* __restrict__ X,
                                                    const float* __restrict__ W,
                                                    const float* __restrict__ dinv,
                                                    float* __restrict__ HS) {
    __shared__ float Wl[HID][HID];   // 64 KB, [k][col]
    __shared__ float Xl[64][132];    // padded stride

    const int tid = threadIdx.x;
    const int row0 = blockIdx.x * 64;

    const float4* Wg = (const float4*)W;
    float4* Wl4 = (float4*)&Wl[0][0];
#pragma unroll
    for (int j = 0; j < 16; ++j) Wl4[tid + j * 256] = Wg[tid + j * 256];

#pragma unroll
    for (int j = 0; j < 8; ++j) {
        int idx = tid + j * 256;
        int r = idx >> 5, p = idx & 31;
        float4 v = make_float4(0.f, 0.f, 0.f, 0.f);
        if (row0 + r < N_NODES) v = ((const float4*)X)[(size_t)(row0 + r) * 32 + p];
        *(float4*)&Xl[r][p * 4] = v;
    }
    __syncthreads();

    const int tx = tid & 15;
    const int ty = tid >> 4;
    const int c0 = tx * 8;
    const int r0 = ty * 4;

    float acc[4][8];
#pragma unroll
    for (int i = 0; i < 4; ++i)
#pragma unroll
        for (int j = 0; j < 8; ++j) acc[i][j] = 0.f;

    for (int k = 0; k < HID; k += 4) {
        float4 xa[4];
#pragma unroll
        for (int i = 0; i < 4; ++i) xa[i] = *(const float4*)&Xl[r0 + i][k];
#pragma unroll
        for (int kk = 0; kk < 4; ++kk) {
            float4 w0 = *(const float4*)&Wl[k + kk][c0];
            float4 w1 = *(const float4*)&Wl[k + kk][c0 + 4];
            float wv[8] = {w0.x, w0.y, w0.z, w0.w, w1.x, w1.y, w1.z, w1.w};
            float xv[4] = {(&xa[0].x)[kk], (&xa[1].x)[kk], (&xa[2].x)[kk], (&xa[3].x)[kk]};
#pragma unroll
            for (int i = 0; i < 4; ++i)
#pragma unroll
                for (int j = 0; j < 8; ++j) acc[i][j] = fmaf(xv[i], wv[j], acc[i][j]);
        }
    }

#pragma unroll
    for (int i = 0; i < 4; ++i) {
        int r = row0 + r0 + i;
        if (r < N_NODES) {
            float dv = dinv[r];
            float4 o0 = make_float4(acc[i][0] * dv, acc[i][1] * dv, acc[i][2] * dv, acc[i][3] * dv);
            float4 o1 = make_float4(acc[i][4] * dv, acc[i][5] * dv, acc[i][6] * dv, acc[i][7] * dv);
            float4* outp = (float4*)&HS[(size_t)r * HID + c0];
            outp[0] = o0;
            outp[1] = o1;
        }
    }
}

// ---------------- fused gather ----------------
// out = [relu](b + dinv[i]*(hs[i] + sum_e hs[csr[e]])); 32 lanes/node

template <bool RELU>
__global__ __launch_bounds__(256) void k_gather(const float* __restrict__ hs,
                                                const int* __restrict__ csr,
                                                const int* __restrict__ offs,
                                                const float* __restrict__ dinv,
                                                const float* __restrict__ bias,
                                                float* __restrict__ out) {
    int t = blockIdx.x * 256 + threadIdx.x;
    int node = t >> 5;
    if (node >= N_NODES) return;
    int c = (t & 31) * 4;

    const float* __restrict__ hc = hs + c;

    float4 a = *(const float4*)&hc[(size_t)node * HID];  // self-loop term
    float4 a2 = make_float4(0.f, 0.f, 0.f, 0.f);
    int e0 = offs[node], e1 = offs[node + 1];

    int e = e0;
    // 4-deep: four independent gathers in flight, two accumulator chains
    for (; e + 4 <= e1; e += 4) {
        int s0 = csr[e], s1 = csr[e + 1], s2 = csr[e + 2], s3 = csr[e + 3];
        float4 v0 = *(const float4*)&hc[(size_t)s0 * HID];
        float4 v1 = *(const float4*)&hc[(size_t)s1 * HID];
        float4 v2 = *(const float4*)&hc[(size_t)s2 * HID];
        float4 v3 = *(const float4*)&hc[(size_t)s3 * HID];
        a.x += v0.x + v1.x;  a.y += v0.y + v1.y;  a.z += v0.z + v1.z;  a.w += v0.w + v1.w;
        a2.x += v2.x + v3.x; a2.y += v2.y + v3.y; a2.z += v2.z + v3.z; a2.w += v2.w + v3.w;
    }
    if (e + 2 <= e1) {
        int s0 = csr[e], s1 = csr[e + 1];
        float4 v0 = *(const float4*)&hc[(size_t)s0 * HID];
        float4 v1 = *(const float4*)&hc[(size_t)s1 * HID];
        a.x += v0.x + v1.x; a.y += v0.y + v1.y; a.z += v0.z + v1.z; a.w += v0.w + v1.w;
        e += 2;
    }
    if (e < e1) {
        int s0 = csr[e];
        float4 v0 = *(const float4*)&hc[(size_t)s0 * HID];
        a.x += v0.x; a.y += v0.y; a.z += v0.z; a.w += v0.w;
    }
    a.x += a2.x; a.y += a2.y; a.z += a2.z; a.w += a2.w;

    float dv = dinv[node];
    float4 bb = *(const float4*)&bias[c];
    float4 o;
    o.x = bb.x + dv * a.x;
    o.y = bb.y + dv * a.y;
    o.z = bb.z + dv * a.z;
    o.w = bb.w + dv * a.w;
    if (RELU) {
        o.x = fmaxf(o.x, 0.f);
        o.y = fmaxf(o.y, 0.f);
        o.z = fmaxf(o.z, 0.f);
        o.w = fmaxf(o.w, 0.f);
    }
    *(float4*)&out[(size_t)node * HID + c] = o;
}

// ---------------- launch ----------------

extern "C" void kernel_launch(void* const* d_in, const int* in_sizes, int n_in,
                              void* d_out, int out_size, void* d_ws, size_t ws_size,
                              hipStream_t stream) {
    const int* edge_index = (const int*)d_in[0];       // [2, E]
    const float* node_emb = (const float*)d_in[1];     // [N, 128]
    const float* W0 = (const float*)d_in[2];
    const float* b0 = (const float*)d_in[3];
    const float* W1 = (const float*)d_in[4];
    const float* b1 = (const float*)d_in[5];
    const float* W2 = (const float*)d_in[6];
    const float* b2 = (const float*)d_in[7];
    float* out = (float*)d_out;

    const int* src = edge_index;            // edge_index[0]
    const int* dst = edge_index + N_EDGES;  // edge_index[1]

    // workspace layout (persistent): dinv | offsets | csr | hs
    float* ws = (float*)d_ws;
    float* dinv = ws;                                   // N floats
    int* offs = (int*)(ws + N_NODES);                   // N+1 ints
    int* csr = (int*)(ws + 2 * N_NODES + 4);            // E ints
    float* hs = ws + 2 * N_NODES + 4 + N_EDGES;         // N*H floats (16B aligned)

    // transient build scratch, overlapped into hs region (build completes
    // before the first GEMM writes hs; single stream => ordered)
    int* deg = (int*)hs;                                // N ints
    int* cursor = deg + N_NODES;                        // N ints
    int* bsum = cursor + N_NODES;                       // SCAN_BLOCKS ints

    const int gemm_blocks = (N_NODES + 63) / 64;            // 782
    const int gath_blocks = (N_NODES * 32 + 255) / 256;     // 6250
    const int edge_blocks = (N_EDGES + 255) / 256;          // 2344
    const int node_blocks = (N_NODES + 255) / 256;          // 196

    // ---- CSR build (once) ----
    hipMemsetAsync(deg, 0, 2 * N_NODES * sizeof(int), stream);  // deg + cursor
    k_count_deg<<<edge_blocks, 256, 0, stream>>>(dst, deg);
    k_make_dinv<<<node_blocks, 256, 0, stream>>>(deg, dinv);
    k_scan1<<<SCAN_BLOCKS, 256, 0, stream>>>(deg, offs, bsum);
    k_scan2<<<1, 256, 0, stream>>>(bsum);
    k_scan3<<<SCAN_BLOCKS, 256, 0, stream>>>(offs, bsum);
    k_fill<<<edge_blocks, 256, 0, stream>>>(src, dst, offs, cursor, csr);

    // ---- layer 0 ----  (d_out doubles as the inter-layer activation buffer)
    k_gemm_scale<<<gemm_blocks, 256, 0, stream>>>(node_emb, W0, dinv, hs);
    k_gather<true><<<gath_blocks, 256, 0, stream>>>(hs, csr, offs, dinv, b0, out);

    // ---- layer 1 ----
    k_gemm_scale<<<gemm_blocks, 256, 0, stream>>>(out, W1, dinv, hs);
    k_gather<true><<<gath_blocks, 256, 0, stream>>>(hs, csr, offs, dinv, b1, out);

    // ---- layer 2 ----
    k_gemm_scale<<<gemm_blocks, 256, 0, stream>>>(out, W2, dinv, hs);
    k_gather<false><<<gath_blocks, 256, 0, stream>>>(hs, csr, offs, dinv, b2, out);
}

// Round 4
// 353.361 us; speedup vs baseline: 9.1105x; 1.0992x over previous
//
#include <hip/hip_runtime.h>

#define N_NODES 50000
#define N_EDGES 600000
#define HID 128
#define SCAN_BLOCKS ((N_NODES + 255) / 256)   // 196

// ---------------- degree ----------------

__global__ __launch_bounds__(256) void k_count_deg(const int* __restrict__ dst,
                                                   int* __restrict__ deg) {
    int e = blockIdx.x * 256 + threadIdx.x;
    if (e < N_EDGES) atomicAdd(&deg[dst[e]], 1);
}

__global__ __launch_bounds__(256) void k_make_dinv(const int* __restrict__ deg,
                                                   float* __restrict__ dinv) {
    int i = blockIdx.x * 256 + threadIdx.x;
    if (i < N_NODES) dinv[i] = rsqrtf((float)(deg[i] + 1));  // +1 self-loop
}

// ---------------- two-level exclusive scan ----------------

__global__ __launch_bounds__(256) void k_scan1(const int* __restrict__ deg,
                                               int* __restrict__ offs,
                                               int* __restrict__ bsum) {
    __shared__ int buf[256];
    const int t = threadIdx.x;
    const int i = blockIdx.x * 256 + t;
    int v = (i < N_NODES) ? deg[i] : 0;
    buf[t] = v;
    __syncthreads();
#pragma unroll
    for (int off = 1; off < 256; off <<= 1) {
        int x = (t >= off) ? buf[t - off] : 0;
        __syncthreads();
        buf[t] += x;
        __syncthreads();
    }
    if (i < N_NODES) offs[i] = buf[t] - v;       // block-local exclusive
    if (t == 255) bsum[blockIdx.x] = buf[255];   // block total
}

__global__ __launch_bounds__(256) void k_scan2(int* __restrict__ bsum) {
    __shared__ int buf[256];
    const int t = threadIdx.x;
    int v = (t < SCAN_BLOCKS) ? bsum[t] : 0;
    buf[t] = v;
    __syncthreads();
#pragma unroll
    for (int off = 1; off < 256; off <<= 1) {
        int x = (t >= off) ? buf[t - off] : 0;
        __syncthreads();
        buf[t] += x;
        __syncthreads();
    }
    if (t < SCAN_BLOCKS) bsum[t] = buf[t] - v;   // exclusive over block sums
}

__global__ __launch_bounds__(256) void k_scan3(int* __restrict__ offs,
                                               const int* __restrict__ bsum) {
    int i = blockIdx.x * 256 + threadIdx.x;
    if (i < N_NODES) offs[i] += bsum[blockIdx.x];
    if (i == 0) offs[N_NODES] = N_EDGES;         // total is known statically
}

// ---------------- CSR fill ----------------

__global__ __launch_bounds__(256) void k_fill(const int* __restrict__ src,
                                              const int* __restrict__ dst,
                                              const int* __restrict__ offs,
                                              int* __restrict__ cursor,
                                              int* __restrict__ csr) {
    int e = blockIdx.x * 256 + threadIdx.x;
    if (e >= N_EDGES) return;
    int d = dst[e];
    int pos = offs[d] + atomicAdd(&cursor[d], 1);
    csr[pos] = src[e];
}

// ---------------- GEMM: hs = (X @ W) * dinv[row] ----------------
// X tile in LDS only (33.8 KB -> 4 blocks/CU); W read from global (L1/L2-cached
// broadcast: every block sweeps the same 64 KB once). block=256, tile 64x128,
// thread = 4 rows x 8 cols.

__global__ __launch_bounds__(256, 4) void k_gemm_scale(const float* __restrict__ X,
                                                       const float* __restrict__ W,
                                                       const float* __restrict__ dinv,
                                                       float* __restrict__ HS) {
    __shared__ float Xl[64][132];    // padded stride; 33792 B

    const int tid = threadIdx.x;
    const int row0 = blockIdx.x * 64;

    // cooperative load X tile (2048 float4), zero-pad OOB rows
#pragma unroll
    for (int j = 0; j < 8; ++j) {
        int idx = tid + j * 256;
        int r = idx >> 5, p = idx & 31;
        float4 v = make_float4(0.f, 0.f, 0.f, 0.f);
        if (row0 + r < N_NODES) v = ((const float4*)X)[(size_t)(row0 + r) * 32 + p];
        *(float4*)&Xl[r][p * 4] = v;
    }
    __syncthreads();

    const int tx = tid & 15;
    const int ty = tid >> 4;
    const int c0 = tx * 8;
    const int r0 = ty * 4;

    const float* __restrict__ Wp = W + c0;   // row k at Wp[k*128], Wp[k*128+4]

    float acc[4][8];
#pragma unroll
    for (int i = 0; i < 4; ++i)
#pragma unroll
        for (int j = 0; j < 8; ++j) acc[i][j] = 0.f;

#pragma unroll 2
    for (int k = 0; k < HID; k += 4) {
        float4 xa[4];
#pragma unroll
        for (int i = 0; i < 4; ++i) xa[i] = *(const float4*)&Xl[r0 + i][k];
#pragma unroll
        for (int kk = 0; kk < 4; ++kk) {
            float4 w0 = *(const float4*)&Wp[(k + kk) * HID];
            float4 w1 = *(const float4*)&Wp[(k + kk) * HID + 4];
            float wv[8] = {w0.x, w0.y, w0.z, w0.w, w1.x, w1.y, w1.z, w1.w};
            float xv[4] = {(&xa[0].x)[kk], (&xa[1].x)[kk], (&xa[2].x)[kk], (&xa[3].x)[kk]};
#pragma unroll
            for (int i = 0; i < 4; ++i)
#pragma unroll
                for (int j = 0; j < 8; ++j) acc[i][j] = fmaf(xv[i], wv[j], acc[i][j]);
        }
    }

#pragma unroll
    for (int i = 0; i < 4; ++i) {
        int r = row0 + r0 + i;
        if (r < N_NODES) {
            float dv = dinv[r];
            float4 o0 = make_float4(acc[i][0] * dv, acc[i][1] * dv, acc[i][2] * dv, acc[i][3] * dv);
            float4 o1 = make_float4(acc[i][4] * dv, acc[i][5] * dv, acc[i][6] * dv, acc[i][7] * dv);
            float4* outp = (float4*)&HS[(size_t)r * HID + c0];
            outp[0] = o0;
            outp[1] = o1;
        }
    }
}

// ---------------- fused gather ----------------
// out = [relu](b + dinv[i]*(hs[i] + sum_e hs[csr[e]])); 32 lanes/node

template <bool RELU>
__global__ __launch_bounds__(256) void k_gather(const float* __restrict__ hs,
                                                const int* __restrict__ csr,
                                                const int* __restrict__ offs,
                                                const float* __restrict__ dinv,
                                                const float* __restrict__ bias,
                                                float* __restrict__ out) {
    int t = blockIdx.x * 256 + threadIdx.x;
    int node = t >> 5;
    if (node >= N_NODES) return;
    int c = (t & 31) * 4;

    const float* __restrict__ hc = hs + c;

    float4 a = *(const float4*)&hc[(size_t)node * HID];  // self-loop term
    float4 a2 = make_float4(0.f, 0.f, 0.f, 0.f);
    int e0 = offs[node], e1 = offs[node + 1];

    int e = e0;
    for (; e + 4 <= e1; e += 4) {
        int s0 = csr[e], s1 = csr[e + 1], s2 = csr[e + 2], s3 = csr[e + 3];
        float4 v0 = *(const float4*)&hc[(size_t)s0 * HID];
        float4 v1 = *(const float4*)&hc[(size_t)s1 * HID];
        float4 v2 = *(const float4*)&hc[(size_t)s2 * HID];
        float4 v3 = *(const float4*)&hc[(size_t)s3 * HID];
        a.x += v0.x + v1.x;  a.y += v0.y + v1.y;  a.z += v0.z + v1.z;  a.w += v0.w + v1.w;
        a2.x += v2.x + v3.x; a2.y += v2.y + v3.y; a2.z += v2.z + v3.z; a2.w += v2.w + v3.w;
    }
    if (e + 2 <= e1) {
        int s0 = csr[e], s1 = csr[e + 1];
        float4 v0 = *(const float4*)&hc[(size_t)s0 * HID];
        float4 v1 = *(const float4*)&hc[(size_t)s1 * HID];
        a.x += v0.x + v1.x; a.y += v0.y + v1.y; a.z += v0.z + v1.z; a.w += v0.w + v1.w;
        e += 2;
    }
    if (e < e1) {
        int s0 = csr[e];
        float4 v0 = *(const float4*)&hc[(size_t)s0 * HID];
        a.x += v0.x; a.y += v0.y; a.z += v0.z; a.w += v0.w;
    }
    a.x += a2.x; a.y += a2.y; a.z += a2.z; a.w += a2.w;

    float dv = dinv[node];
    float4 bb = *(const float4*)&bias[c];
    float4 o;
    o.x = bb.x + dv * a.x;
    o.y = bb.y + dv * a.y;
    o.z = bb.z + dv * a.z;
    o.w = bb.w + dv * a.w;
    if (RELU) {
        o.x = fmaxf(o.x, 0.f);
        o.y = fmaxf(o.y, 0.f);
        o.z = fmaxf(o.z, 0.f);
        o.w = fmaxf(o.w, 0.f);
    }
    *(float4*)&out[(size_t)node * HID + c] = o;
}

// ---------------- launch ----------------

extern "C" void kernel_launch(void* const* d_in, const int* in_sizes, int n_in,
                              void* d_out, int out_size, void* d_ws, size_t ws_size,
                              hipStream_t stream) {
    const int* edge_index = (const int*)d_in[0];       // [2, E]
    const float* node_emb = (const float*)d_in[1];     // [N, 128]
    const float* W0 = (const float*)d_in[2];
    const float* b0 = (const float*)d_in[3];
    const float* W1 = (const float*)d_in[4];
    const float* b1 = (const float*)d_in[5];
    const float* W2 = (const float*)d_in[6];
    const float* b2 = (const float*)d_in[7];
    float* out = (float*)d_out;

    const int* src = edge_index;            // edge_index[0]
    const int* dst = edge_index + N_EDGES;  // edge_index[1]

    // workspace layout (persistent): dinv | offsets | csr | hs
    float* ws = (float*)d_ws;
    float* dinv = ws;                                   // N floats
    int* offs = (int*)(ws + N_NODES);                   // N+1 ints
    int* csr = (int*)(ws + 2 * N_NODES + 4);            // E ints
    float* hs = ws + 2 * N_NODES + 4 + N_EDGES;         // N*H floats (16B aligned)

    // transient build scratch, overlapped into hs region (build completes
    // before the first GEMM writes hs; single stream => ordered)
    int* deg = (int*)hs;                                // N ints
    int* cursor = deg + N_NODES;                        // N ints
    int* bsum = cursor + N_NODES;                       // SCAN_BLOCKS ints

    const int gemm_blocks = (N_NODES + 63) / 64;            // 782
    const int gath_blocks = (N_NODES * 32 + 255) / 256;     // 6250
    const int edge_blocks = (N_EDGES + 255) / 256;          // 2344
    const int node_blocks = (N_NODES + 255) / 256;          // 196

    // ---- CSR build (once) ----
    hipMemsetAsync(deg, 0, 2 * N_NODES * sizeof(int), stream);  // deg + cursor
    k_count_deg<<<edge_blocks, 256, 0, stream>>>(dst, deg);
    k_make_dinv<<<node_blocks, 256, 0, stream>>>(deg, dinv);
    k_scan1<<<SCAN_BLOCKS, 256, 0, stream>>>(deg, offs, bsum);
    k_scan2<<<1, 256, 0, stream>>>(bsum);
    k_scan3<<<SCAN_BLOCKS, 256, 0, stream>>>(offs, bsum);
    k_fill<<<edge_blocks, 256, 0, stream>>>(src, dst, offs, cursor, csr);

    // ---- layer 0 ----  (d_out doubles as the inter-layer activation buffer)
    k_gemm_scale<<<gemm_blocks, 256, 0, stream>>>(node_emb, W0, dinv, hs);
    k_gather<true><<<gath_blocks, 256, 0, stream>>>(hs, csr, offs, dinv, b0, out);

    // ---- layer 1 ----
    k_gemm_scale<<<gemm_blocks, 256, 0, stream>>>(out, W1, dinv, hs);
    k_gather<true><<<gath_blocks, 256, 0, stream>>>(hs, csr, offs, dinv, b1, out);

    // ---- layer 2 ----
    k_gemm_scale<<<gemm_blocks, 256, 0, stream>>>(out, W2, dinv, hs);
    k_gather<false><<<gath_blocks, 256, 0, stream>>>(hs, csr, offs, dinv, b2, out);
}

// Round 5
// 287.716 us; speedup vs baseline: 11.1892x; 1.2282x over previous
//
#include <hip/hip_runtime.h>
#include <hip/hip_fp16.h>

#define N_NODES 50000
#define N_EDGES 600000
#define HID 128
#define SCAN_BLOCKS ((N_NODES + 255) / 256)   // 196

// ---------------- degree ----------------

__global__ __launch_bounds__(256) void k_count_deg(const int* __restrict__ dst,
                                                   int* __restrict__ deg) {
    int e = blockIdx.x * 256 + threadIdx.x;
    if (e < N_EDGES) atomicAdd(&deg[dst[e]], 1);
}

__global__ __launch_bounds__(256) void k_make_dinv(const int* __restrict__ deg,
                                                   float* __restrict__ dinv) {
    int i = blockIdx.x * 256 + threadIdx.x;
    if (i < N_NODES) dinv[i] = rsqrtf((float)(deg[i] + 1));  // +1 self-loop
}

// ---------------- two-level exclusive scan ----------------

__global__ __launch_bounds__(256) void k_scan1(const int* __restrict__ deg,
                                               int* __restrict__ offs,
                                               int* __restrict__ bsum) {
    __shared__ int buf[256];
    const int t = threadIdx.x;
    const int i = blockIdx.x * 256 + t;
    int v = (i < N_NODES) ? deg[i] : 0;
    buf[t] = v;
    __syncthreads();
#pragma unroll
    for (int off = 1; off < 256; off <<= 1) {
        int x = (t >= off) ? buf[t - off] : 0;
        __syncthreads();
        buf[t] += x;
        __syncthreads();
    }
    if (i < N_NODES) offs[i] = buf[t] - v;       // block-local exclusive
    if (t == 255) bsum[blockIdx.x] = buf[255];   // block total
}

__global__ __launch_bounds__(256) void k_scan2(int* __restrict__ bsum) {
    __shared__ int buf[256];
    const int t = threadIdx.x;
    int v = (t < SCAN_BLOCKS) ? bsum[t] : 0;
    buf[t] = v;
    __syncthreads();
#pragma unroll
    for (int off = 1; off < 256; off <<= 1) {
        int x = (t >= off) ? buf[t - off] : 0;
        __syncthreads();
        buf[t] += x;
        __syncthreads();
    }
    if (t < SCAN_BLOCKS) bsum[t] = buf[t] - v;   // exclusive over block sums
}

__global__ __launch_bounds__(256) void k_scan3(int* __restrict__ offs,
                                               const int* __restrict__ bsum) {
    int i = blockIdx.x * 256 + threadIdx.x;
    if (i < N_NODES) offs[i] += bsum[blockIdx.x];
    if (i == 0) offs[N_NODES] = N_EDGES;         // total is known statically
}

// ---------------- CSR fill ----------------

__global__ __launch_bounds__(256) void k_fill(const int* __restrict__ src,
                                              const int* __restrict__ dst,
                                              const int* __restrict__ offs,
                                              int* __restrict__ cursor,
                                              int* __restrict__ csr) {
    int e = blockIdx.x * 256 + threadIdx.x;
    if (e >= N_EDGES) return;
    int d = dst[e];
    int pos = offs[d] + atomicAdd(&cursor[d], 1);
    csr[pos] = src[e];
}

// ---------------- GEMM: hs = fp16( (X @ W) * dinv[row] ) ----------------
// X tile in LDS (33.8 KB -> 4 blocks/CU); W from global (L1/L2 broadcast).
// block=256, tile 64x128, thread = 4 rows x 8 cols. Output packed fp16.

union Pack8 {
    _Float16 h[8];
    uint4 u;
};

__global__ __launch_bounds__(256, 4) void k_gemm_scale(const float* __restrict__ X,
                                                       const float* __restrict__ W,
                                                       const float* __restrict__ dinv,
                                                       _Float16* __restrict__ HS) {
    __shared__ float Xl[64][132];    // padded stride; 33792 B

    const int tid = threadIdx.x;
    const int row0 = blockIdx.x * 64;

#pragma unroll
    for (int j = 0; j < 8; ++j) {
        int idx = tid + j * 256;
        int r = idx >> 5, p = idx & 31;
        float4 v = make_float4(0.f, 0.f, 0.f, 0.f);
        if (row0 + r < N_NODES) v = ((const float4*)X)[(size_t)(row0 + r) * 32 + p];
        *(float4*)&Xl[r][p * 4] = v;
    }
    __syncthreads();

    const int tx = tid & 15;
    const int ty = tid >> 4;
    const int c0 = tx * 8;
    const int r0 = ty * 4;

    const float* __restrict__ Wp = W + c0;

    float acc[4][8];
#pragma unroll
    for (int i = 0; i < 4; ++i)
#pragma unroll
        for (int j = 0; j < 8; ++j) acc[i][j] = 0.f;

#pragma unroll 2
    for (int k = 0; k < HID; k += 4) {
        float4 xa[4];
#pragma unroll
        for (int i = 0; i < 4; ++i) xa[i] = *(const float4*)&Xl[r0 + i][k];
#pragma unroll
        for (int kk = 0; kk < 4; ++kk) {
            float4 w0 = *(const float4*)&Wp[(k + kk) * HID];
            float4 w1 = *(const float4*)&Wp[(k + kk) * HID + 4];
            float wv[8] = {w0.x, w0.y, w0.z, w0.w, w1.x, w1.y, w1.z, w1.w};
            float xv[4] = {(&xa[0].x)[kk], (&xa[1].x)[kk], (&xa[2].x)[kk], (&xa[3].x)[kk]};
#pragma unroll
            for (int i = 0; i < 4; ++i)
#pragma unroll
                for (int j = 0; j < 8; ++j) acc[i][j] = fmaf(xv[i], wv[j], acc[i][j]);
        }
    }

#pragma unroll
    for (int i = 0; i < 4; ++i) {
        int r = row0 + r0 + i;
        if (r < N_NODES) {
            float dv = dinv[r];
            Pack8 pk;
#pragma unroll
            for (int j = 0; j < 8; ++j) pk.h[j] = (_Float16)(acc[i][j] * dv);
            *(uint4*)&HS[(size_t)r * HID + c0] = pk.u;
        }
    }
}

// ---------------- fused gather (fp16 source, fp32 accumulate) ----------------
// out = [relu](b + dinv[i]*(hs[i] + sum_e hs[csr[e]])); 16 lanes/node, 8 cols/lane

template <bool RELU>
__global__ __launch_bounds__(256) void k_gather(const _Float16* __restrict__ hs,
                                                const int* __restrict__ csr,
                                                const int* __restrict__ offs,
                                                const float* __restrict__ dinv,
                                                const float* __restrict__ bias,
                                                float* __restrict__ out) {
    int t = blockIdx.x * 256 + threadIdx.x;
    int node = t >> 4;
    if (node >= N_NODES) return;
    int c = (t & 15) * 8;

    const _Float16* __restrict__ hc = hs + c;

    float a[8], a2[8];
    {
        Pack8 v = *(const Pack8*)&hc[(size_t)node * HID];  // self-loop term
#pragma unroll
        for (int j = 0; j < 8; ++j) { a[j] = (float)v.h[j]; a2[j] = 0.f; }
    }
    int e0 = offs[node], e1 = offs[node + 1];

    int e = e0;
    for (; e + 4 <= e1; e += 4) {
        int s0 = csr[e], s1 = csr[e + 1], s2 = csr[e + 2], s3 = csr[e + 3];
        Pack8 v0 = *(const Pack8*)&hc[(size_t)s0 * HID];
        Pack8 v1 = *(const Pack8*)&hc[(size_t)s1 * HID];
        Pack8 v2 = *(const Pack8*)&hc[(size_t)s2 * HID];
        Pack8 v3 = *(const Pack8*)&hc[(size_t)s3 * HID];
#pragma unroll
        for (int j = 0; j < 8; ++j) {
            a[j] += (float)v0.h[j] + (float)v1.h[j];
            a2[j] += (float)v2.h[j] + (float)v3.h[j];
        }
    }
    if (e + 2 <= e1) {
        int s0 = csr[e], s1 = csr[e + 1];
        Pack8 v0 = *(const Pack8*)&hc[(size_t)s0 * HID];
        Pack8 v1 = *(const Pack8*)&hc[(size_t)s1 * HID];
#pragma unroll
        for (int j = 0; j < 8; ++j) a[j] += (float)v0.h[j] + (float)v1.h[j];
        e += 2;
    }
    if (e < e1) {
        int s0 = csr[e];
        Pack8 v0 = *(const Pack8*)&hc[(size_t)s0 * HID];
#pragma unroll
        for (int j = 0; j < 8; ++j) a[j] += (float)v0.h[j];
    }

    float dv = dinv[node];
    float4 b0 = *(const float4*)&bias[c];
    float4 b1 = *(const float4*)&bias[c + 4];
    float bb[8] = {b0.x, b0.y, b0.z, b0.w, b1.x, b1.y, b1.z, b1.w};
    float o[8];
#pragma unroll
    for (int j = 0; j < 8; ++j) {
        float x = bb[j] + dv * (a[j] + a2[j]);
        o[j] = RELU ? fmaxf(x, 0.f) : x;
    }
    float4* op = (float4*)&out[(size_t)node * HID + c];
    op[0] = make_float4(o[0], o[1], o[2], o[3]);
    op[1] = make_float4(o[4], o[5], o[6], o[7]);
}

// ---------------- launch ----------------

extern "C" void kernel_launch(void* const* d_in, const int* in_sizes, int n_in,
                              void* d_out, int out_size, void* d_ws, size_t ws_size,
                              hipStream_t stream) {
    const int* edge_index = (const int*)d_in[0];       // [2, E]
    const float* node_emb = (const float*)d_in[1];     // [N, 128]
    const float* W0 = (const float*)d_in[2];
    const float* b0 = (const float*)d_in[3];
    const float* W1 = (const float*)d_in[4];
    const float* b1 = (const float*)d_in[5];
    const float* W2 = (const float*)d_in[6];
    const float* b2 = (const float*)d_in[7];
    float* out = (float*)d_out;

    const int* src = edge_index;            // edge_index[0]
    const int* dst = edge_index + N_EDGES;  // edge_index[1]

    // workspace layout (persistent): dinv | offsets | csr | hs(fp16)
    float* ws = (float*)d_ws;
    float* dinv = ws;                                   // N floats
    int* offs = (int*)(ws + N_NODES);                   // N+1 ints
    int* csr = (int*)(ws + 2 * N_NODES + 4);            // E ints
    _Float16* hs = (_Float16*)(ws + 2 * N_NODES + 4 + N_EDGES);  // N*H halves, 16B aligned

    // transient build scratch, overlapped into hs region (build completes
    // before the first GEMM writes hs; single stream => ordered)
    int* deg = (int*)hs;                                // N ints
    int* cursor = deg + N_NODES;                        // N ints
    int* bsum = cursor + N_NODES;                       // SCAN_BLOCKS ints

    const int gemm_blocks = (N_NODES + 63) / 64;            // 782
    const int gath_blocks = (N_NODES * 16 + 255) / 256;     // 3125
    const int edge_blocks = (N_EDGES + 255) / 256;          // 2344
    const int node_blocks = (N_NODES + 255) / 256;          // 196

    // ---- CSR build (once) ----
    hipMemsetAsync(deg, 0, 2 * N_NODES * sizeof(int), stream);  // deg + cursor
    k_count_deg<<<edge_blocks, 256, 0, stream>>>(dst, deg);
    k_make_dinv<<<node_blocks, 256, 0, stream>>>(deg, dinv);
    k_scan1<<<SCAN_BLOCKS, 256, 0, stream>>>(deg, offs, bsum);
    k_scan2<<<1, 256, 0, stream>>>(bsum);
    k_scan3<<<SCAN_BLOCKS, 256, 0, stream>>>(offs, bsum);
    k_fill<<<edge_blocks, 256, 0, stream>>>(src, dst, offs, cursor, csr);

    // ---- layer 0 ----  (d_out doubles as the inter-layer activation buffer)
    k_gemm_scale<<<gemm_blocks, 256, 0, stream>>>(node_emb, W0, dinv, hs);
    k_gather<true><<<gath_blocks, 256, 0, stream>>>(hs, csr, offs, dinv, b0, out);

    // ---- layer 1 ----
    k_gemm_scale<<<gemm_blocks, 256, 0, stream>>>(out, W1, dinv, hs);
    k_gather<true><<<gath_blocks, 256, 0, stream>>>(hs, csr, offs, dinv, b1, out);

    // ---- layer 2 ----
    k_gemm_scale<<<gemm_blocks, 256, 0, stream>>>(out, W2, dinv, hs);
    k_gather<false><<<gath_blocks, 256, 0, stream>>>(hs, csr, offs, dinv, b2, out);
}

// Round 7
// 212.156 us; speedup vs baseline: 15.1742x; 1.3562x over previous
//
#include <hip/hip_runtime.h>
#include <hip/hip_fp16.h>

#define N_NODES 50000
#define N_EDGES 600000
#define HID 128
#define SCAN_BLOCKS ((N_NODES + 255) / 256)   // 196

typedef _Float16 half8 __attribute__((ext_vector_type(8)));
typedef float f32x4 __attribute__((ext_vector_type(4)));

union Pack8 {
    _Float16 h[8];
    uint4 u;
};

// ---------------- zero scratch (replaces pathological rocclr fill) ----------------

__global__ __launch_bounds__(256) void k_zero(int* __restrict__ p, int n) {
    int i = blockIdx.x * 256 + threadIdx.x;
    if (i < n) p[i] = 0;
}

// ---------------- degree ----------------

__global__ __launch_bounds__(256) void k_count_deg(const int* __restrict__ dst,
                                                   int* __restrict__ deg) {
    int e = blockIdx.x * 256 + threadIdx.x;
    if (e < N_EDGES) atomicAdd(&deg[dst[e]], 1);
}

__global__ __launch_bounds__(256) void k_make_dinv(const int* __restrict__ deg,
                                                   float* __restrict__ dinv) {
    int i = blockIdx.x * 256 + threadIdx.x;
    if (i < N_NODES) dinv[i] = rsqrtf((float)(deg[i] + 1));  // +1 self-loop
}

// ---------------- two-level exclusive scan ----------------

__global__ __launch_bounds__(256) void k_scan1(const int* __restrict__ deg,
                                               int* __restrict__ offs,
                                               int* __restrict__ bsum) {
    __shared__ int buf[256];
    const int t = threadIdx.x;
    const int i = blockIdx.x * 256 + t;
    int v = (i < N_NODES) ? deg[i] : 0;
    buf[t] = v;
    __syncthreads();
#pragma unroll
    for (int off = 1; off < 256; off <<= 1) {
        int x = (t >= off) ? buf[t - off] : 0;
        __syncthreads();
        buf[t] += x;
        __syncthreads();
    }
    if (i < N_NODES) offs[i] = buf[t] - v;
    if (t == 255) bsum[blockIdx.x] = buf[255];
}

__global__ __launch_bounds__(256) void k_scan2(int* __restrict__ bsum) {
    __shared__ int buf[256];
    const int t = threadIdx.x;
    int v = (t < SCAN_BLOCKS) ? bsum[t] : 0;
    buf[t] = v;
    __syncthreads();
#pragma unroll
    for (int off = 1; off < 256; off <<= 1) {
        int x = (t >= off) ? buf[t - off] : 0;
        __syncthreads();
        buf[t] += x;
        __syncthreads();
    }
    if (t < SCAN_BLOCKS) bsum[t] = buf[t] - v;
}

__global__ __launch_bounds__(256) void k_scan3(int* __restrict__ offs,
                                               const int* __restrict__ bsum) {
    int i = blockIdx.x * 256 + threadIdx.x;
    if (i < N_NODES) offs[i] += bsum[blockIdx.x];
    if (i == 0) offs[N_NODES] = N_EDGES;
}

// ---------------- CSR fill ----------------

__global__ __launch_bounds__(256) void k_fill(const int* __restrict__ src,
                                              const int* __restrict__ dst,
                                              const int* __restrict__ offs,
                                              int* __restrict__ cursor,
                                              int* __restrict__ csr) {
    int e = blockIdx.x * 256 + threadIdx.x;
    if (e >= N_EDGES) return;
    int d = dst[e];
    int pos = offs[d] + atomicAdd(&cursor[d], 1);
    csr[pos] = src[e];
}

// ---------------- W prep: Wt[l][n][k] = fp16(W_l[k][n]) ----------------

__global__ __launch_bounds__(256) void k_prep_w(const float* __restrict__ W0,
                                                const float* __restrict__ W1,
                                                const float* __restrict__ W2,
                                                _Float16* __restrict__ Wt) {
    int i = blockIdx.x * 256 + threadIdx.x;
    if (i >= 3 * HID * HID) return;
    int l = i >> 14;
    int r = i & 16383;
    int n = r >> 7, k = r & 127;
    const float* W = (l == 0) ? W0 : (l == 1) ? W1 : W2;
    Wt[i] = (_Float16)W[k * HID + n];
}

// ---------------- MFMA GEMM: hs = fp16( (X @ W) * dinv[row] ) ----------------
// block = 256 (4 waves), tile 64 rows x 128 cols; wave = 16 rows x 128 cols.
// A-frag: lane l -> row l&15, 8 contiguous k at (l>>4)*8 (+ks*32). B-frag: col
// l&15 from Wt rows, same k map (k-permutation cancels between A and B).
// D: col=l&15, row=(l>>4)*4+reg  [m89-verified].

template <typename TIN>
__global__ __launch_bounds__(256) void k_gemm_mfma(const TIN* __restrict__ X,
                                                   const _Float16* __restrict__ Wt,  // [128][128] n-major
                                                   const float* __restrict__ dinv,
                                                   _Float16* __restrict__ HS) {
    __shared__ _Float16 Xl[64][136];    // 17408 B (pad 136 -> 2-way bank alias, free)
    __shared__ _Float16 Wl[128][136];   // 34816 B

    const int tid = threadIdx.x;
    const int row0 = blockIdx.x * 64;

    // ---- stage X tile as fp16 ----
    if constexpr (sizeof(TIN) == 4) {  // fp32 input (layer 0)
#pragma unroll
        for (int j = 0; j < 8; ++j) {
            int idx = tid + j * 256;              // 2048 float4
            int r = idx >> 5, p = idx & 31;
            float4 v = make_float4(0.f, 0.f, 0.f, 0.f);
            if (row0 + r < N_NODES) v = ((const float4*)X)[(size_t)(row0 + r) * 32 + p];
            _Float16* d = &Xl[r][p * 4];
            d[0] = (_Float16)v.x; d[1] = (_Float16)v.y;
            d[2] = (_Float16)v.z; d[3] = (_Float16)v.w;
        }
    } else {  // fp16 input (layers 1,2)
#pragma unroll
        for (int j = 0; j < 4; ++j) {
            int idx = tid + j * 256;              // 1024 uint4
            int r = idx >> 4, p = idx & 15;
            uint4 v = make_uint4(0, 0, 0, 0);
            if (row0 + r < N_NODES) v = ((const uint4*)X)[(size_t)(row0 + r) * 16 + p];
            *(uint4*)&Xl[r][p * 8] = v;
        }
    }
    // ---- stage Wt (whole 128x128 = 2048 uint4) ----
#pragma unroll
    for (int j = 0; j < 8; ++j) {                 // FIX: was j<4 (half of W unstaged)
        int idx = tid + j * 256;
        int r = idx >> 4, p = idx & 15;
        *(uint4*)&Wl[r][p * 8] = ((const uint4*)Wt)[idx];
    }
    __syncthreads();

    const int w = tid >> 6;      // wave 0..3 -> rows w*16..+15
    const int l = tid & 63;
    const int m16 = l & 15;
    const int kg = l >> 4;       // 0..3

    f32x4 acc[8];
#pragma unroll
    for (int nt = 0; nt < 8; ++nt) acc[nt] = (f32x4)(0.f);

#pragma unroll
    for (int ks = 0; ks < 4; ++ks) {
        half8 a = *(const half8*)&Xl[w * 16 + m16][kg * 8 + ks * 32];
#pragma unroll
        for (int nt = 0; nt < 8; ++nt) {
            half8 b = *(const half8*)&Wl[nt * 16 + m16][kg * 8 + ks * 32];
            acc[nt] = __builtin_amdgcn_mfma_f32_16x16x32_f16(a, b, acc[nt], 0, 0, 0);
        }
    }

    // ---- epilogue: scale by dinv, store fp16 ----
    const int rbase = row0 + w * 16 + kg * 4;
    float4 dv4 = *(const float4*)&dinv[rbase];  // tail-block overread stays inside ws
#pragma unroll
    for (int j = 0; j < 4; ++j) {
        int r = rbase + j;
        if (r < N_NODES) {
            float dv = ((const float*)&dv4)[j];
#pragma unroll
            for (int nt = 0; nt < 8; ++nt)
                HS[(size_t)r * HID + nt * 16 + m16] = (_Float16)(acc[nt][j] * dv);
        }
    }
}

// ---------------- fused gather (fp16 source, fp32 accumulate) ----------------
// out = [relu](b + dinv[i]*(hs[i] + sum_e hs[csr[e]])); 16 lanes/node, 8 cols/lane
// TOUT = _Float16 (inter-layer) or float (final output)

template <bool RELU, typename TOUT>
__global__ __launch_bounds__(256) void k_gather(const _Float16* __restrict__ hs,
                                                const int* __restrict__ csr,
                                                const int* __restrict__ offs,
                                                const float* __restrict__ dinv,
                                                const float* __restrict__ bias,
                                                TOUT* __restrict__ out) {
    int t = blockIdx.x * 256 + threadIdx.x;
    int node = t >> 4;
    if (node >= N_NODES) return;
    int c = (t & 15) * 8;

    const _Float16* __restrict__ hc = hs + c;

    float a[8], a2[8];
    {
        Pack8 v;
        v.u = *(const uint4*)&hc[(size_t)node * HID];
#pragma unroll
        for (int j = 0; j < 8; ++j) { a[j] = (float)v.h[j]; a2[j] = 0.f; }
    }
    int e0 = offs[node], e1 = offs[node + 1];

    int e = e0;
    for (; e + 4 <= e1; e += 4) {
        int s0 = csr[e], s1 = csr[e + 1], s2 = csr[e + 2], s3 = csr[e + 3];
        Pack8 v0, v1, v2, v3;
        v0.u = *(const uint4*)&hc[(size_t)s0 * HID];
        v1.u = *(const uint4*)&hc[(size_t)s1 * HID];
        v2.u = *(const uint4*)&hc[(size_t)s2 * HID];
        v3.u = *(const uint4*)&hc[(size_t)s3 * HID];
#pragma unroll
        for (int j = 0; j < 8; ++j) {
            a[j] += (float)v0.h[j] + (float)v1.h[j];
            a2[j] += (float)v2.h[j] + (float)v3.h[j];
        }
    }
    if (e + 2 <= e1) {
        int s0 = csr[e], s1 = csr[e + 1];
        Pack8 v0, v1;
        v0.u = *(const uint4*)&hc[(size_t)s0 * HID];
        v1.u = *(const uint4*)&hc[(size_t)s1 * HID];
#pragma unroll
        for (int j = 0; j < 8; ++j) a[j] += (float)v0.h[j] + (float)v1.h[j];
        e += 2;
    }
    if (e < e1) {
        int s0 = csr[e];
        Pack8 v0;
        v0.u = *(const uint4*)&hc[(size_t)s0 * HID];
#pragma unroll
        for (int j = 0; j < 8; ++j) a[j] += (float)v0.h[j];
    }

    float dv = dinv[node];
    float4 b0 = *(const float4*)&bias[c];
    float4 b1 = *(const float4*)&bias[c + 4];
    float bb[8] = {b0.x, b0.y, b0.z, b0.w, b1.x, b1.y, b1.z, b1.w};
    float o[8];
#pragma unroll
    for (int j = 0; j < 8; ++j) {
        float x = bb[j] + dv * (a[j] + a2[j]);
        o[j] = RELU ? fmaxf(x, 0.f) : x;
    }
    if constexpr (sizeof(TOUT) == 2) {
        Pack8 pk;
#pragma unroll
        for (int j = 0; j < 8; ++j) pk.h[j] = (_Float16)o[j];
        *(uint4*)&out[(size_t)node * HID + c] = pk.u;
    } else {
        float4* op = (float4*)&out[(size_t)node * HID + c];
        op[0] = make_float4(o[0], o[1], o[2], o[3]);
        op[1] = make_float4(o[4], o[5], o[6], o[7]);
    }
}

// ---------------- launch ----------------

extern "C" void kernel_launch(void* const* d_in, const int* in_sizes, int n_in,
                              void* d_out, int out_size, void* d_ws, size_t ws_size,
                              hipStream_t stream) {
    const int* edge_index = (const int*)d_in[0];       // [2, E]
    const float* node_emb = (const float*)d_in[1];     // [N, 128]
    const float* W0 = (const float*)d_in[2];
    const float* b0 = (const float*)d_in[3];
    const float* W1 = (const float*)d_in[4];
    const float* b1 = (const float*)d_in[5];
    const float* W2 = (const float*)d_in[6];
    const float* b2 = (const float*)d_in[7];
    float* out = (float*)d_out;

    const int* src = edge_index;            // edge_index[0]
    const int* dst = edge_index + N_EDGES;  // edge_index[1]

    // workspace layout (float units):
    //   dinv [0,50000) | offs [50000,100004) | csr [100004,700004)
    //   hs   [700004, 3900004)  (N*HID fp16)
    //   Wt   [3900004, 3912292) (3*128*128 fp16)
    float* ws = (float*)d_ws;
    float* dinv = ws;
    int* offs = (int*)(ws + 50000);
    int* csr = (int*)(ws + 100004);
    _Float16* hs = (_Float16*)(ws + 700004);
    _Float16* Wt = (_Float16*)(ws + 3900004);

    // transient CSR-build scratch aliased into hs region (done before first GEMM)
    int* deg = (int*)hs;                                // N ints
    int* cursor = deg + N_NODES;                        // N ints
    int* bsum = cursor + N_NODES;                       // SCAN_BLOCKS ints

    // inter-layer fp16 activations live in d_out scratch (overwritten by final layer)
    _Float16* xh = (_Float16*)d_out;

    const int gemm_blocks = (N_NODES + 63) / 64;            // 782
    const int gath_blocks = (N_NODES * 16 + 255) / 256;     // 3125
    const int edge_blocks = (N_EDGES + 255) / 256;          // 2344
    const int node_blocks = (N_NODES + 255) / 256;          // 196
    const int zero_blocks = (2 * N_NODES + 255) / 256;      // 391
    const int prep_blocks = (3 * HID * HID + 255) / 256;    // 192

    // ---- CSR build + W prep (once) ----
    k_zero<<<zero_blocks, 256, 0, stream>>>(deg, 2 * N_NODES);   // deg + cursor
    k_count_deg<<<edge_blocks, 256, 0, stream>>>(dst, deg);
    k_make_dinv<<<node_blocks, 256, 0, stream>>>(deg, dinv);
    k_scan1<<<SCAN_BLOCKS, 256, 0, stream>>>(deg, offs, bsum);
    k_scan2<<<1, 256, 0, stream>>>(bsum);
    k_scan3<<<SCAN_BLOCKS, 256, 0, stream>>>(offs, bsum);
    k_fill<<<edge_blocks, 256, 0, stream>>>(src, dst, offs, cursor, csr);
    k_prep_w<<<prep_blocks, 256, 0, stream>>>(W0, W1, W2, Wt);

    // ---- layer 0 ----
    k_gemm_mfma<float><<<gemm_blocks, 256, 0, stream>>>(node_emb, Wt, dinv, hs);
    k_gather<true, _Float16><<<gath_blocks, 256, 0, stream>>>(hs, csr, offs, dinv, b0, xh);

    // ---- layer 1 ----
    k_gemm_mfma<_Float16><<<gemm_blocks, 256, 0, stream>>>(xh, Wt + 16384, dinv, hs);
    k_gather<true, _Float16><<<gath_blocks, 256, 0, stream>>>(hs, csr, offs, dinv, b1, xh);

    // ---- layer 2 ----
    k_gemm_mfma<_Float16><<<gemm_blocks, 256, 0, stream>>>(xh, Wt + 32768, dinv, hs);
    k_gather<false, float><<<gath_blocks, 256, 0, stream>>>(hs, csr, offs, dinv, b2, out);
}